// Round 14
// baseline (339.357 us; speedup 1.0000x reference)
//
#include <hip/hip_runtime.h>

#define T_LEN 8000
#define NTPB 125
#define NBLK 250
#define NLAYER 30
#define GUARD 512
#define HROWS (GUARD + T_LEN)
#define SLAB (HROWS * 128)          // shorts per h slab (level,batch)
#define INV_SQRT2 0.70710678118f

typedef short bf16x8 __attribute__((ext_vector_type(8)));
typedef unsigned uint2v __attribute__((ext_vector_type(2)));
typedef unsigned uint4v __attribute__((ext_vector_type(4)));
typedef float f32x4 __attribute__((ext_vector_type(4)));
typedef float f32x16 __attribute__((ext_vector_type(16)));

// ---- LDS layout (shorts). slot = 512 shorts (64 t x 8 ch) ----
#define R_HT  0          // h[t] 16 slots; x tile spans slots 0..31
#define R_OUT 8192       // gated out / y
#define R_CND 16384      // cond (12 slots; k=80 -> 1.0 bias col)
#define WB0   22528      // weight stage buf 0 (16384 shorts = 32 KB)
#define WB1   38912      // weight stage buf 1
#define LDS_SHORTS 55296 // 108 KB

// ---- weight pack: per layer 208 frags of 512 shorts (32x32x16 A-frags) ----
// frag order: d1/g [ks0-7][2mat][4chf] (0-63), c/cg [ks0-5][2mat][4chf] (64-111),
//             d0 [ks0-7][4chf] (112-143), r/s [ks0-7][2mat][4chf] (144-207)
#define LS 106496
#define C1 16384
#define C2 32768
#define C3 49152
#define C4 57344
#define C5 73728
#define C6 90112
#define IN_OFF   3194880
#define OUT1_OFF 3227648
#define OUT2_OFF 3244032

__device__ __forceinline__ unsigned short f2bf_u(float f) {
    union { float f; unsigned u; } v; v.f = f;
    unsigned u = v.u + 0x7FFFu + ((v.u >> 16) & 1u);
    return (unsigned short)(u >> 16);
}
__device__ __forceinline__ short f2bf(float f) { return (short)f2bf_u(f); }

__device__ __forceinline__ unsigned cvtpk(float lo, float hi) {
    unsigned r;
    asm("v_cvt_pk_bf16_f32 %0, %1, %2" : "=v"(r) : "v"(lo), "v"(hi));
    return r;
}
__device__ __forceinline__ float gated_act(float av, float gv) {
    float e  = __expf(-2.f * fabsf(av));
    float th = (1.f - e) * __builtin_amdgcn_rcpf(1.f + e);
    th = (av < 0.f) ? -th : th;
    float sg = __builtin_amdgcn_rcpf(1.f + __expf(-gv));
    return th * sg;
}
__device__ __forceinline__ void ldg16_sc1(bf16x8* d, const short* p) {
    asm volatile("global_load_dwordx4 %0, %1, off sc1" : "=v"(*d) : "v"(p));
}
__device__ __forceinline__ void stg8_sc1(short* p, uint2v v) {
    asm volatile("global_store_dwordx2 %0, %1, off sc1" : : "v"(p), "v"(v) : "memory");
}
__device__ __forceinline__ void st_flag(int* p, int v) {
    __hip_atomic_store(p, v, __ATOMIC_RELAXED, __HIP_MEMORY_SCOPE_AGENT);
}
__device__ __forceinline__ void wait_ge(const int* p, int v) {
    while (__hip_atomic_load(p, __ATOMIC_RELAXED, __HIP_MEMORY_SCOPE_AGENT) < v)
        __builtin_amdgcn_s_sleep(1);
}
__device__ __forceinline__ f32x16 mfma32(bf16x8 a, bf16x8 b, f32x16 c) {
    return __builtin_amdgcn_mfma_f32_32x32x16_bf16(a, b, c, 0, 0, 0);
}
__device__ __forceinline__ f32x16 zero16() {
    f32x16 z = {0.f,0.f,0.f,0.f,0.f,0.f,0.f,0.f,0.f,0.f,0.f,0.f,0.f,0.f,0.f,0.f};
    return z;
}
__device__ __forceinline__ void gload_lds16(const short* g, short* l) {
    __builtin_amdgcn_global_load_lds(
        (const __attribute__((address_space(1))) unsigned int*)g,
        (__attribute__((address_space(3))) unsigned int*)l, 16, 0, 0);
}
// 8-wave staging: 32 KB chunk (4 issues/lane) / 16 KB (2 issues)
__device__ __forceinline__ void stage32(const short* src, short* dst, int wv, int lane) {
#pragma unroll
    for (int r = 0; r < 4; ++r) {
        int s = (r * 8 + wv) * 512;
        gload_lds16(src + s + lane * 8, dst + s);
    }
}
__device__ __forceinline__ void stage16(const short* src, short* dst, int wv, int lane) {
#pragma unroll
    for (int r = 0; r < 2; ++r) {
        int s = (r * 8 + wv) * 512;
        gload_lds16(src + s + lane * 8, dst + s);
    }
}

// pair gemm: chunk [p][2mat][4chf]; B from LDS (kb = 2*ksg + hi), shared by both mats
template<int NP>
__device__ __forceinline__ void pair32(const short* wb, const short* sm, int breg,
                                       int ks0, int boff, int awoff,
                                       f32x16& acA, f32x16& acG)
{
#pragma unroll
    for (int p = 0; p < NP; ++p) {
        bf16x8 B = *(const bf16x8*)&sm[breg + (ks0 + p) * 1024 + boff];
        bf16x8 a0 = *(const bf16x8*)&wb[p * 4096 + awoff];
        acA = mfma32(a0, B, acA);
        bf16x8 a1 = *(const bf16x8*)&wb[p * 4096 + 2048 + awoff];
        acG = mfma32(a1, B, acG);
    }
}
// single gemm: chunk [p][4chf]
template<int NP>
__device__ __forceinline__ void single32(const short* wb, const short* sm, int breg,
                                         int ks0, int boff, int awoff, f32x16& ac)
{
#pragma unroll
    for (int p = 0; p < NP; ++p) {
        bf16x8 B = *(const bf16x8*)&sm[breg + (ks0 + p) * 1024 + boff];
        bf16x8 a = *(const bf16x8*)&wb[p * 2048 + awoff];
        ac = mfma32(a, B, ac);
    }
}

// ---------------- weight pack + flag/guard zero ----------------
__global__ __launch_bounds__(256) void k_pack(
    const float* __restrict__ dil_w, const float* __restrict__ gate_w,
    const float* __restrict__ cond_w, const float* __restrict__ condg_w,
    const float* __restrict__ res_w, const float* __restrict__ skip_w,
    const float* __restrict__ input_w, const float* __restrict__ out1_w,
    const float* __restrict__ out2_w,
    const float* __restrict__ dil_b, const float* __restrict__ cond_b,
    const float* __restrict__ gate_b, const float* __restrict__ condg_b,
    short* __restrict__ wp, short* __restrict__ hbt, int* __restrict__ flg)
{
    int gid = blockIdx.x * 256 + threadIdx.x;
    if (gid < 512) flg[gid] = 0;
    {
        int g2 = gid - 512;
        if (g2 >= 0 && g2 < 262144) {      // zero guard rows of 8 slabs
            unsigned* hb32 = (unsigned*)hbt;
            int slab = g2 >> 15, off = g2 & 32767;
            hb32[(size_t)slab * (SLAB / 2) + off] = 0u;
        }
    }
    if (gid >= 6400 * 64) return;
    int fid = gid >> 6, lane = gid & 63;
    int l31 = lane & 31, hi = lane >> 5;
    float v[8];
    if (fid < 6240) {
        int layer = fid / 208;
        int fr = fid - layer * 208;
        int mat, ks, chf;
        if (fr < 64)       { ks = fr >> 3; int rem = fr & 7;  mat = (rem < 4) ? 1 : 2; chf = rem & 3; }
        else if (fr < 112) { int f2 = fr - 64;  ks = f2 >> 3; int rem = f2 & 7; mat = (rem < 4) ? 3 : 4; chf = rem & 3; }
        else if (fr < 144) { int f2 = fr - 112; ks = f2 >> 2; chf = f2 & 3; mat = 0; }
        else               { int f2 = fr - 144; ks = f2 >> 3; int rem = f2 & 7; mat = (rem < 4) ? 5 : 6; chf = rem & 3; }
        int m = chf * 32 + l31;
        size_t mi = (size_t)layer * 128 + m;
        int kb = ks * 16 + hi * 8;
#pragma unroll
        for (int e = 0; e < 8; ++e) {
            int k = kb + e;
            float val;
            switch (mat) {
                case 0:  val = dil_w[(mi * 128 + k) * 2];     break;
                case 1:  val = dil_w[(mi * 128 + k) * 2 + 1]; break;
                case 2:  val = gate_w[mi * 128 + k]; break;
                case 3:  val = (k < 80) ? cond_w[mi * 80 + k]
                               : ((k == 80) ? dil_b[mi] + cond_b[mi] : 0.f); break;
                case 4:  val = (k < 80) ? condg_w[mi * 80 + k]
                               : ((k == 80) ? gate_b[mi] + condg_b[mi] : 0.f); break;
                case 5:  val = res_w[mi * 128 + k]; break;
                default: val = skip_w[mi * 128 + k]; break;
            }
            v[e] = val;
        }
    } else if (fid < 6304) {               // input conv: [ks0-15][4chf]
        int f = fid - 6240; int ks = f >> 2, chf = f & 3;
        int m = chf * 32 + l31; int kb = ks * 16 + hi * 8;
#pragma unroll
        for (int e = 0; e < 8; ++e) v[e] = input_w[(size_t)m * 256 + kb + e];
    } else if (fid < 6336) {               // out1: [ks0-7][4chf]
        int f = fid - 6304; int ks = f >> 2, chf = f & 3;
        int m = chf * 32 + l31; int kb = ks * 16 + hi * 8;
#pragma unroll
        for (int e = 0; e < 8; ++e) v[e] = out1_w[(size_t)m * 128 + kb + e];
    } else {                               // out2: [ks0-7][8chf]
        int f = fid - 6336; int ks = f >> 3, chf = f & 7;
        int m = chf * 32 + l31; int kb = ks * 16 + hi * 8;
#pragma unroll
        for (int e = 0; e < 8; ++e) v[e] = out2_w[(size_t)m * 128 + kb + e];
    }
    short* dst = wp + (size_t)fid * 512 + lane * 8;
#pragma unroll
    for (int e = 0; e < 8; ++e) dst[e] = f2bf(v[e]);
}

// ---------------- persistent fused WaveNet: 8 waves, 32x32x16 frags ----------------
__global__ __launch_bounds__(512, 2) void k_wavenet(
    const float* __restrict__ x, const float* __restrict__ cond,
    const short* __restrict__ wp, short* __restrict__ hbt,
    const float* __restrict__ ib, const float* __restrict__ rbias,
    const float* __restrict__ sbias, const float* __restrict__ b1,
    const float* __restrict__ b2, float* __restrict__ outp,
    int* __restrict__ rdy, int* __restrict__ dn)
{
    __shared__ __align__(16) short sm[LDS_SHORTS];   // 108 KB

    const int tid  = threadIdx.x;
    const int lane = tid & 63;
    const int wv   = __builtin_amdgcn_readfirstlane(tid >> 6);   // 0..7
    const int wm   = wv & 3;            // 32-ch group
    const int wt   = wv >> 2;           // 32-t group
    const int l31  = lane & 31;
    const int hi   = lane >> 5;
    const int bidx = blockIdx.x;
    const int b    = bidx / NTPB;
    const int ti   = bidx - b * NTPB;
    const int t0   = ti * 64;
    const int tloc = wt * 32 + l31;
    const int tg   = t0 + tloc;
    const int lane8 = lane * 8;
    const int awoff = wm * 512 + lane8;           // A-frag offset within kline
    const int boff  = hi * 512 + tloc * 8;        // B offset: (2ks+hi) slot + t
    const int chW   = wm * 32 + 4 * hi;           // writeback ch base (+8q+j)

    // ---- stage input-conv weights (2 chunks) + x tile + cond ----
    stage32(wp + IN_OFF, (short*)&sm[WB0], wv, lane);
    stage32(wp + IN_OFF + 16384, (short*)&sm[WB1], wv, lane);
    {
        const float* xb = x + (size_t)b * 256 * T_LEN + t0 + lane;
#pragma unroll
        for (int it = 0; it < 4; ++it) {
            int kb = wv * 4 + it;              // 0..31
            unsigned pk[4];
#pragma unroll
            for (int e = 0; e < 4; ++e)
                pk[e] = cvtpk(xb[(size_t)(kb * 8 + 2 * e) * T_LEN],
                              xb[(size_t)(kb * 8 + 2 * e + 1) * T_LEN]);
            *(uint4v*)&sm[(kb * 64 + lane) * 8] = *(uint4v*)pk;
        }
        if (wv < 6) {
            const float* cb = cond + (size_t)b * 80 * T_LEN + t0 + lane;
#pragma unroll
            for (int it = 0; it < 2; ++it) {
                int kb = wv * 2 + it;          // 0..11
                unsigned pk[4];
#pragma unroll
                for (int e = 0; e < 4; ++e) {
                    int c0 = kb * 8 + 2 * e, c1 = c0 + 1;
                    float v0 = (c0 < 80) ? cb[(size_t)c0 * T_LEN] : ((c0 == 80) ? 1.f : 0.f);
                    float v1 = (c1 < 80) ? cb[(size_t)c1 * T_LEN] : 0.f;
                    pk[e] = cvtpk(v0, v1);
                }
                *(uint4v*)&sm[R_CND + (kb * 64 + lane) * 8] = *(uint4v*)pk;
            }
        }
    }
    __syncthreads();

    // ---- input conv: h0 = Win @ x + ib ----
    f32x16 hres;
    {
        f32x16 acc = zero16();
        single32<8>((const short*)&sm[WB0], sm, 0, 0, boff, awoff, acc);
        single32<8>((const short*)&sm[WB1], sm, 0, 8, boff, awoff, acc);
        __syncthreads();   // all waves done reading x slots
        const float* ibp = ib + chW;
#pragma unroll
        for (int q = 0; q < 4; ++q) {
            f32x4 bv = *(const f32x4*)&ibp[8 * q];
#pragma unroll
            for (int j = 0; j < 4; ++j) hres[4 * q + j] = acc[4 * q + j] + bv[j];
        }
        short* hrow = hbt + (size_t)b * SLAB + (size_t)(GUARD + tg) * 128 + chW;
#pragma unroll
        for (int q = 0; q < 4; ++q) {
            uint2v hv = {cvtpk(hres[4*q], hres[4*q+1]), cvtpk(hres[4*q+2], hres[4*q+3])};
            stg8_sc1(hrow + 8 * q, hv);
            *(uint2v*)&sm[R_HT + ((wm * 4 + q) * 64 + tloc) * 8 + 4 * hi] = hv;
        }
    }
    asm volatile("s_waitcnt vmcnt(0)" ::: "memory");
    __syncthreads();
    if (tid == 0) st_flag(&rdy[bidx], 1);

    f32x16 skp = zero16();

    // ---- 30 layers (R13 skeleton, 32x32 frags) ----
    for (int li = 0; li < NLAYER; ++li) {
        const int d   = 1 << (li % 10);
        const int ksh = (d + 63) >> 6;
        const short* wl  = wp + (size_t)li * LS;
        const short* hcb = hbt + (size_t)((li & 3) * 2 + b) * SLAB;
        short*       hnb = hbt + (size_t)(((li + 1) & 3) * 2 + b) * SLAB;

        stage32(wl, (short*)&sm[WB0], wv, lane);                       // S0: d1/g ks0-3
        __syncthreads();                                               // barA
        stage32(wl + C1, (short*)&sm[WB1], wv, lane);                  // S1: d1/g ks4-7
        f32x16 aa = zero16(), ag = zero16();
        pair32<4>((const short*)&sm[WB0], sm, R_HT, 0, boff, awoff, aa, ag);   // c0
        __syncthreads();                                               // barB
        stage32(wl + C2, (short*)&sm[WB0], wv, lane);                  // S2: c/cg ks0-3
        pair32<4>((const short*)&sm[WB1], sm, R_HT, 4, boff, awoff, aa, ag);   // c1
        __syncthreads();                                               // barC
        stage16(wl + C3, (short*)&sm[WB1], wv, lane);                  // S3: c/cg ks4-5
        pair32<4>((const short*)&sm[WB0], sm, R_CND, 0, boff, awoff, aa, ag);  // c2
        __syncthreads();                                               // barD
        stage32(wl + C4, (short*)&sm[WB0], wv, lane);                  // S4: d0
        // dependency wait + h[t-d] B-frags (late placement)
        if (lane == 0 && ti >= ksh) wait_ge(&rdy[bidx - ksh], li + 1);
        bf16x8 Bg[8];
        {
            const short* hr = hcb + (size_t)(GUARD + tg - d) * 128 + hi * 8;
#pragma unroll
            for (int ks = 0; ks < 8; ++ks) ldg16_sc1(&Bg[ks], hr + ks * 16);
        }
        pair32<2>((const short*)&sm[WB1], sm, R_CND, 4, boff, awoff, aa, ag);  // c3
        __syncthreads();                                               // barE: S4+Bg landed
        if (tid == 0) st_flag(&dn[bidx], li + 1);
        stage32(wl + C5, (short*)&sm[WB1], wv, lane);                  // S5: r/s ks0-3
        {   // c4: d0 @ Bg
            const short* wb = (const short*)&sm[WB0];
#pragma unroll
            for (int ks = 0; ks < 8; ++ks) {
                bf16x8 a = *(const bf16x8*)&wb[ks * 2048 + awoff];
                aa = mfma32(a, Bg[ks], aa);
            }
        }
        {   // act -> R_OUT
            float o[16];
#pragma unroll
            for (int i = 0; i < 16; ++i) o[i] = gated_act(aa[i], ag[i]);
#pragma unroll
            for (int q = 0; q < 4; ++q) {
                uint2v ov = {cvtpk(o[4*q], o[4*q+1]), cvtpk(o[4*q+2], o[4*q+3])};
                *(uint2v*)&sm[R_OUT + ((wm * 4 + q) * 64 + tloc) * 8 + 4 * hi] = ov;
            }
        }
        __syncthreads();                                               // barF: S5 ready, R_OUT visible
        stage32(wl + C6, (short*)&sm[WB0], wv, lane);                  // S6: r/s ks4-7
        f32x16 ar = zero16(), as2 = zero16();
        pair32<4>((const short*)&sm[WB1], sm, R_OUT, 0, boff, awoff, ar, as2); // c5
        __syncthreads();                                               // barG
        pair32<4>((const short*)&sm[WB0], sm, R_OUT, 4, boff, awoff, ar, as2); // c6

        {
            const float* rbl = rbias + li * 128 + chW;
            const float* sbl = sbias + li * 128 + chW;
#pragma unroll
            for (int q = 0; q < 4; ++q) {
                f32x4 rbv = *(const f32x4*)&rbl[8 * q];
                f32x4 sbv = *(const f32x4*)&sbl[8 * q];
#pragma unroll
                for (int j = 0; j < 4; ++j) {
                    int i = 4 * q + j;
                    skp[i]  = skp[i] + as2[i] + sbv[j];
                    hres[i] = (hres[i] + ar[i] + rbv[j]) * INV_SQRT2;
                }
            }
        }
        if (li < NLAYER - 1) {
            if (lane == 0 && li >= 3) {        // WAR vs readers of h^{li-3}
                int d3 = 1 << ((li - 3) % 10);
                int k3 = (d3 + 63) >> 6;
                if (ti + k3 < NTPB) wait_ge(&dn[bidx + k3], li - 2);
            }
            short* hrow = hnb + (size_t)(GUARD + tg) * 128 + chW;
#pragma unroll
            for (int q = 0; q < 4; ++q) {
                uint2v hv = {cvtpk(hres[4*q], hres[4*q+1]), cvtpk(hres[4*q+2], hres[4*q+3])};
                stg8_sc1(hrow + 8 * q, hv);
                *(uint2v*)&sm[R_HT + ((wm * 4 + q) * 64 + tloc) * 8 + 4 * hi] = hv;
            }
        }
        asm volatile("s_waitcnt vmcnt(0)" ::: "memory");
        __syncthreads();                                               // barH
        if (tid == 0 && li < NLAYER - 1) st_flag(&rdy[bidx], li + 2);
    }

    // ---- output head ----
#pragma unroll
    for (int q = 0; q < 4; ++q) {              // skip -> R_HT (bf16)
        uint2v sv = {cvtpk(skp[4*q], skp[4*q+1]), cvtpk(skp[4*q+2], skp[4*q+3])};
        *(uint2v*)&sm[R_HT + ((wm * 4 + q) * 64 + tloc) * 8 + 4 * hi] = sv;
    }
    stage32(wp + OUT1_OFF, (short*)&sm[WB0], wv, lane);
    stage32(wp + OUT2_OFF, (short*)&sm[WB1], wv, lane);
    __syncthreads();                           // skip visible; out1 + out2a ready
    f32x16 ay = zero16();
    single32<8>((const short*)&sm[WB0], sm, R_HT, 0, boff, awoff, ay);
    {
        const float* b1p = b1 + chW;
#pragma unroll
        for (int q = 0; q < 4; ++q) {          // y = relu(. + b1) -> R_OUT
            f32x4 bv = *(const f32x4*)&b1p[8 * q];
            float y0 = fmaxf(ay[4*q]   + bv[0], 0.f);
            float y1 = fmaxf(ay[4*q+1] + bv[1], 0.f);
            float y2 = fmaxf(ay[4*q+2] + bv[2], 0.f);
            float y3 = fmaxf(ay[4*q+3] + bv[3], 0.f);
            uint2v yv = {cvtpk(y0, y1), cvtpk(y2, y3)};
            *(uint2v*)&sm[R_OUT + ((wm * 4 + q) * 64 + tloc) * 8 + 4 * hi] = yv;
        }
    }
    __syncthreads();                           // y visible; WB0 free
    stage32(wp + OUT2_OFF + 16384, (short*)&sm[WB0], wv, lane);
    f32x16 ao0 = zero16(), ao1 = zero16();
    {
        const short* wb = (const short*)&sm[WB1];   // out2 ks0-3
#pragma unroll
        for (int p = 0; p < 4; ++p) {
            bf16x8 B = *(const bf16x8*)&sm[R_OUT + p * 1024 + boff];
            bf16x8 a0 = *(const bf16x8*)&wb[p * 4096 + wm * 512 + lane8];
            ao0 = mfma32(a0, B, ao0);
            bf16x8 a1 = *(const bf16x8*)&wb[p * 4096 + (wm + 4) * 512 + lane8];
            ao1 = mfma32(a1, B, ao1);
        }
    }
    __syncthreads();                           // out2b ready
    {
        const short* wb = (const short*)&sm[WB0];   // out2 ks4-7
#pragma unroll
        for (int p = 0; p < 4; ++p) {
            bf16x8 B = *(const bf16x8*)&sm[R_OUT + (4 + p) * 1024 + boff];
            bf16x8 a0 = *(const bf16x8*)&wb[p * 4096 + wm * 512 + lane8];
            ao0 = mfma32(a0, B, ao0);
            bf16x8 a1 = *(const bf16x8*)&wb[p * 4096 + (wm + 4) * 512 + lane8];
            ao1 = mfma32(a1, B, ao1);
        }
    }
#pragma unroll
    for (int q = 0; q < 4; ++q) {
#pragma unroll
        for (int j = 0; j < 4; ++j) {
            int ch = chW + 8 * q + j;
            outp[((size_t)(b * 256 + ch)) * T_LEN + tg]       = ao0[4*q+j] + b2[ch];
            outp[((size_t)(b * 256 + ch + 128)) * T_LEN + tg] = ao1[4*q+j] + b2[ch + 128];
        }
    }
}

extern "C" void kernel_launch(void* const* d_in, const int* in_sizes, int n_in,
                              void* d_out, int out_size, void* d_ws, size_t ws_size,
                              hipStream_t stream)
{
    const float* x       = (const float*)d_in[0];
    const float* cond    = (const float*)d_in[1];
    const float* input_w = (const float*)d_in[2];
    const float* input_b = (const float*)d_in[3];
    const float* dil_w   = (const float*)d_in[4];
    const float* dil_b   = (const float*)d_in[5];
    const float* gate_w  = (const float*)d_in[6];
    const float* gate_b  = (const float*)d_in[7];
    const float* cond_w  = (const float*)d_in[8];
    const float* cond_b  = (const float*)d_in[9];
    const float* condg_w = (const float*)d_in[10];
    const float* condg_b = (const float*)d_in[11];
    const float* res_w   = (const float*)d_in[12];
    const float* res_b   = (const float*)d_in[13];
    const float* skip_w  = (const float*)d_in[14];
    const float* skip_b  = (const float*)d_in[15];
    const float* out1_w  = (const float*)d_in[16];
    const float* out1_b  = (const float*)d_in[17];
    const float* out2_w  = (const float*)d_in[18];
    const float* out2_b  = (const float*)d_in[19];
    float* outp = (float*)d_out;

    short* wpk = (short*)d_ws;                         // 6400*512 shorts
    short* hbt = wpk + (size_t)6400 * 512;             // 8 slabs (4 levels x 2 batches)
    int*   flg = (int*)(hbt + (size_t)8 * SLAB);       // 512 ints
    int*   rdy = flg;
    int*   dn  = flg + 256;

    k_pack<<<1600, 256, 0, stream>>>(dil_w, gate_w, cond_w, condg_w, res_w, skip_w,
                                     input_w, out1_w, out2_w,
                                     dil_b, cond_b, gate_b, condg_b, wpk, hbt, flg);

    void* args[] = {(void*)&x, (void*)&cond, (void*)&wpk, (void*)&hbt,
                    (void*)&input_b, (void*)&res_b, (void*)&skip_b,
                    (void*)&out1_b, (void*)&out2_b, (void*)&outp,
                    (void*)&rdy, (void*)&dn};
    (void)hipLaunchCooperativeKernel((void*)k_wavenet, dim3(NBLK), dim3(512), args, 0, stream);
}